// Round 12
// baseline (336.027 us; speedup 1.0000x reference)
//
#include <hip/hip_runtime.h>

typedef float f32x4 __attribute__((ext_vector_type(4)));
typedef float f32x2 __attribute__((ext_vector_type(2)));
typedef _Float16 f16x8 __attribute__((ext_vector_type(8)));
typedef _Float16 f16x4 __attribute__((ext_vector_type(4)));
typedef _Float16 f16x2 __attribute__((ext_vector_type(2)));

__device__ __forceinline__ float tanh_fast(float x) {
  float e = __builtin_amdgcn_exp2f(x * 2.885390081777927f);
  return 1.0f - 2.0f * __builtin_amdgcn_rcpf(e + 1.0f);
}

// Device-scope dataflow sync (XCD-safe: agent-scope release/acquire).
__device__ __forceinline__ void wait_cnt(int* p, int target) {
  if (threadIdx.x == 0) {
    while (__hip_atomic_load(p, __ATOMIC_RELAXED, __HIP_MEMORY_SCOPE_AGENT) < target)
      __builtin_amdgcn_s_sleep(2);
    (void)__hip_atomic_load(p, __ATOMIC_ACQUIRE, __HIP_MEMORY_SCOPE_AGENT);
  }
  __syncthreads();
}
__device__ __forceinline__ void publish_cnt(int* p) {
  __syncthreads();   // full vmcnt/lgkm drain: all threads' stores complete
  if (threadIdx.x == 0)
    (void)__hip_atomic_fetch_add(p, 1, __ATOMIC_RELEASE, __HIP_MEMORY_SCOPE_AGENT);
}

// ---------------------------------------------------------------------------
// Plain transpose + cast fp32 -> f16:  out[C][R] = (f16) in[R][C]
// ---------------------------------------------------------------------------
__global__ __launch_bounds__(256) void k_transpose_cast(
    const float* __restrict__ in, _Float16* __restrict__ outp, int R, int C)
{
  __shared__ float tile[32][33];
  const int tx = threadIdx.x & 31, ty = threadIdx.x >> 5;
  const int tc = blockIdx.x * 32, tr = blockIdx.y * 32;
#pragma unroll
  for (int i = 0; i < 32; i += 8)
    tile[ty + i][tx] = in[(size_t)(tr + ty + i) * C + tc + tx];
  __syncthreads();
#pragma unroll
  for (int i = 0; i < 32; i += 8)
    outp[(size_t)(tc + ty + i) * R + tr + tx] = (_Float16)tile[tx][ty + i];
}

// ---------------------------------------------------------------------------
// Permuted transpose + cast: out[c][pinv(r)] = (f16) in[r][c]
// pinv(r) = (r&~31) | ((r&15)<<1) | ((r>>4)&1)    (32-block k-permutation)
// ---------------------------------------------------------------------------
__global__ __launch_bounds__(256) void k_transpose_cast_perm(
    const float* __restrict__ in, _Float16* __restrict__ outp, int R, int C)
{
  __shared__ float tile[32][33];
  const int tx = threadIdx.x & 31, ty = threadIdx.x >> 5;
  const int tc = blockIdx.x * 32, tr = blockIdx.y * 32;
#pragma unroll
  for (int i = 0; i < 32; i += 8)
    tile[ty + i][tx] = in[(size_t)(tr + ty + i) * C + tc + tx];
  __syncthreads();
  const int r = tr + tx;
  const int p = (r & ~31) | ((r & 15) << 1) | ((r >> 4) & 1);
#pragma unroll
  for (int i = 0; i < 32; i += 8)
    outp[(size_t)(tc + ty + i) * R + p] = (_Float16)tile[tx][ty + i];
}

// ===========================================================================
// FUSED persistent kernel: 256 blocks x 512 threads, 84KB dyn LDS -> 1/CU.
//   0..7     scan (R7-champion body, chunked 16 x 32 steps, pub/sub sync)
//   8..191   persistent GEMM1 (512 tiles; publishes cnt1[tc] per tile)
//   192..255 persistent GEMM3+softmax (1024 tiles; waits sc[chunk])
// ===========================================================================
__global__ __launch_bounds__(512, 1) void k_fused(
    const float* __restrict__ X, const _Float16* __restrict__ WxT,
    const float* __restrict__ bias, float* __restrict__ xp_packed,
    const _Float16* __restrict__ WhTp, _Float16* __restrict__ Yt,
    float* __restrict__ hT,
    const _Float16* __restrict__ WdTp, const float* __restrict__ bd,
    float* __restrict__ out, int* cnt1, int* sc)
{
  extern __shared__ char smem[];
  const int bid = blockIdx.x;
  const int tid = threadIdx.x;
  const int lane = tid & 63, w = tid >> 6;
  const int l15 = lane & 15, lq = lane >> 4;

  if (bid < 8) {
    // ----------------------------- SCAN ---------------------------------
    const int g = bid;
    char* hz = smem;                       // 2 x 4224 B h ping-pong
    for (int i = tid; i < 2112; i += 512) ((float*)hz)[i] = 0.f;

    f16x8 bf[2][8];
#pragma unroll
    for (int j = 0; j < 2; ++j)
#pragma unroll
      for (int i = 0; i < 8; ++i) {
        int ks = (w + i) & 7;
        bf[j][i] = *(const f16x8*)(WhTp + (w * 32 + j * 16 + l15) * 256 + ks * 32 + lq * 8);
      }

    const int rd_base = (l15 & 3) * 1056 + w * 64 + lq * 16;
    const int wr_base = lq * 1056 + w * 64 + l15 * 4;
    const bool m1 = (lq & 1) != 0, m2 = (lq & 2) != 0;

    const float* xpb = xp_packed + ((size_t)g * 8 + w) * 128 + lane * 2;
    _Float16* yb = Yt + ((size_t)(g * 4 + lq)) * 256 + w * 32 + l15 * 2;
    float* hTb = hT + (g * 4 + lq) * 256 + w * 32 + l15;

    wait_cnt(cnt1 + 0, 32);                // xp chunk 0 ready (also syncs init)

    f32x2 x0 = *(const f32x2*)(xpb);
    f32x2 x1 = *(const f32x2*)(xpb + 8192);

#define SCAN_STEP(T, CUR, Xv, LAST)                                            \
  {                                                                            \
    const int t = (T);                                                         \
    f16x8 af[8];                                                               \
    af[0] = *(const f16x8*)(hz + rd_base + (CUR) * 4224 + 0 * 64);             \
    asm volatile("" ::: "memory");                                             \
    __builtin_amdgcn_s_barrier();                                              \
    asm volatile("" ::: "memory");                                             \
    _Pragma("unroll")                                                          \
    for (int i = 1; i < 8; ++i)                                                \
      af[i] = *(const f16x8*)(hz + rd_base + (CUR) * 4224 + i * 64);           \
    f32x2 xcur = Xv;                                                           \
    f32x4 acc[2][4];                                                           \
    _Pragma("unroll")                                                          \
    for (int j = 0; j < 2; ++j) {                                              \
      _Pragma("unroll")                                                        \
      for (int c2 = 0; c2 < 4; ++c2) {                                         \
        f32x4 zz = {0.f, 0.f, 0.f, 0.f};                                       \
        acc[j][c2] = __builtin_amdgcn_mfma_f32_16x16x32_f16(af[2 * c2], bf[j][2 * c2], zz, 0, 0, 0); \
      }                                                                        \
    }                                                                          \
    { int tn = t + 2; if (tn > 511) tn = 511;                                  \
      Xv = *(const f32x2*)(xpb + (size_t)tn * 8192); }                         \
    _Pragma("unroll")                                                          \
    for (int j = 0; j < 2; ++j) {                                              \
      _Pragma("unroll")                                                        \
      for (int c2 = 0; c2 < 4; ++c2)                                           \
        acc[j][c2] = __builtin_amdgcn_mfma_f32_16x16x32_f16(af[2 * c2 + 1], bf[j][2 * c2 + 1], acc[j][c2], 0, 0, 0); \
    }                                                                          \
    f16x2 h2;                                                                  \
    float vv[2];                                                               \
    _Pragma("unroll")                                                          \
    for (int j = 0; j < 2; ++j) {                                              \
      f32x4 s01 = acc[j][0] + acc[j][1];                                       \
      f32x4 s23 = acc[j][2] + acc[j][3];                                       \
      f32x4 s = s01 + s23;                                                     \
      float t0 = m1 ? s[1] : s[0];                                             \
      float t1 = m1 ? s[3] : s[2];                                             \
      float v = tanh_fast((m2 ? t1 : t0) + xcur[j]);                           \
      vv[j] = v;                                                               \
      h2[j] = (_Float16)v;                                                     \
    }                                                                          \
    *(f16x2*)(hz + wr_base + ((CUR) ^ 1) * 4224) = h2;                         \
    *(f16x2*)(hz + wr_base + ((CUR) ^ 1) * 4224 + 512) = h2;                   \
    *(f16x2*)(yb + (size_t)t * 8192) = h2;                                     \
    if (LAST) { hTb[0] = vv[0]; hTb[16] = vv[1]; }                             \
    asm volatile("s_waitcnt lgkmcnt(0)" ::: "memory");                         \
  }

    for (int c = 0; c < 16; ++c) {
      wait_cnt(cnt1 + (c < 15 ? c + 1 : 15), 32);   // xp for chunk c+1 (prefetch)
      for (int tp = 0; tp < 16; ++tp) {
        SCAN_STEP(c * 32 + 2 * tp,     0, x0, 0)
        SCAN_STEP(c * 32 + 2 * tp + 1, 1, x1, (c == 15 && tp == 15))
      }
      publish_cnt(sc + c);                           // Yt chunk c visible
    }
#undef SCAN_STEP

  } else if (bid < 192) {
    // --------------------- GEMM1 (512-thread version) -------------------
    // BM=32, BN=256, BK=64. Waves: wm=w&1 (m-tile), wn=w>>1 (64-col group).
    // xp_packed idx = ((t*8+g)*8 + w_s)*128 + (lq_s*16+i_s)*2 + j_s
    const int p = bid - 8;                 // 0..183
    _Float16 (*As)[72] = (_Float16(*)[72])smem;                 // 32 x 72
    _Float16 (*Bs)[72] = (_Float16(*)[72])(smem + 4608);        // 256 x 72
    const int wm = w & 1, wn = w >> 1;     // wm 0..1, wn 0..3

    for (int v = p; v < 512; v += 184) {
      const int tc = v >> 5, b = v & 31;
      const int m0 = b * 512 + tc * 32;

      f32x4 acc[4];
#pragma unroll
      for (int i = 0; i < 4; ++i) acc[i] = (f32x4){0.f, 0.f, 0.f, 0.f};

      for (int kc = 0; kc < 16; ++kc) {
        const int k0 = kc * 64;
        __syncthreads();                   // protect As/Bs from prior readers
        {                                  // stage A: 32 x 64, 1 f32x4/thread
          int r = tid >> 4, k4 = (tid & 15) * 4;
          f32x4 vv = *(const f32x4*)(X + (size_t)(m0 + r) * 1024 + k0 + k4);
          f16x4 hv;
          hv[0] = (_Float16)vv[0]; hv[1] = (_Float16)vv[1];
          hv[2] = (_Float16)vv[2]; hv[3] = (_Float16)vv[3];
          *(f16x4*)(&As[r][k4]) = hv;
        }
#pragma unroll
        for (int it = 0; it < 4; ++it) {   // stage B: 256 x 64 f16
          int q = tid + it * 512;          // 0..2047
          int n = q >> 3, k8 = (q & 7) * 8;
          *(f16x8*)(&Bs[n][k8]) = *(const f16x8*)(WxT + (size_t)n * 1024 + k0 + k8);
        }
        __syncthreads();
        f16x8 a[2];
#pragma unroll
        for (int ks = 0; ks < 2; ++ks)
          a[ks] = *(const f16x8*)(&As[wm * 16 + l15][ks * 32 + lq * 8]);
#pragma unroll
        for (int ct = 0; ct < 4; ++ct) {
#pragma unroll
          for (int ks = 0; ks < 2; ++ks) {
            f16x8 bfr = *(const f16x8*)(&Bs[wn * 64 + ct * 16 + l15][ks * 32 + lq * 8]);
            acc[ct] = __builtin_amdgcn_mfma_f32_16x16x32_f16(a[ks], bfr, acc[ct], 0, 0, 0);
          }
        }
      }
#pragma unroll
      for (int ct = 0; ct < 4; ++ct) {
        int ncol = wn * 64 + ct * 16 + l15;          // < 256
        float bvv = bias[ncol];
        int w_s = ncol >> 5, j_s = (ncol >> 4) & 1, i_s = ncol & 15;
#pragma unroll
        for (int r = 0; r < 4; ++r) {
          int m = m0 + wm * 16 + lq * 4 + r;         // m = b*512 + t
          int tt = m & 511, bb = m >> 9;
          int g_s = bb >> 2, lq_s = bb & 3;
          size_t idx = (((size_t)tt * 8 + g_s) * 8 + w_s) * 128 + (lq_s * 16 + i_s) * 2 + j_s;
          xp_packed[idx] = acc[ct][r] + bvv;
        }
      }
      publish_cnt(cnt1 + tc);
    }

  } else {
    // ------------------------- GEMM3 + softmax --------------------------
    const int q = bid - 192;               // 0..63
    _Float16 (*As)[264]  = (_Float16(*)[264])smem;               // 16 x 264
    _Float16 (*Bs)[136]  = (_Float16(*)[136])(smem + 8448);      // 128 x 136
    _Float16 (*lg)[1040] = (_Float16(*)[1040])(smem + 43264);    // 16 x 1040

    for (int v = q; v < 1024; v += 64) {
      const int b = v & 31, t0 = (v >> 5) * 16;
      const int m0 = b * 512 + t0;
      wait_cnt(sc + (t0 >> 5), 8);         // Yt chunk ready (also LDS-reuse sync)

      {
        int r = tid >> 5, k8 = (tid & 31) * 8;
        *(f16x8*)(&As[r][k8]) = *(const f16x8*)(Yt + ((size_t)(t0 + r) * 32 + b) * 256 + k8);
      }
      __syncthreads();
      f16x8 a[8];
#pragma unroll
      for (int ks = 0; ks < 8; ++ks)
        a[ks] = *(const f16x8*)(&As[l15][ks * 32 + lq * 8]);

      for (int cc = 0; cc < 8; ++cc) {
        const int c0 = cc * 128;
        const int ncol = c0 + w * 16 + l15;
        f32x4 acc = {0.f, 0.f, 0.f, 0.f};
        __syncthreads();
#pragma unroll
        for (int i = 0; i < 4; ++i) {
          int q2 = i * 512 + tid;
          int n = q2 >> 4, k8 = (q2 & 15) * 8;
          *(f16x8*)(&Bs[n][k8]) = *(const f16x8*)(WdTp + (size_t)(c0 + n) * 256 + k8);
        }
        __syncthreads();
#pragma unroll
        for (int ks = 0; ks < 4; ++ks) {
          f16x8 bfr = *(const f16x8*)(&Bs[w * 16 + l15][ks * 32 + lq * 8]);
          acc = __builtin_amdgcn_mfma_f32_16x16x32_f16(a[ks], bfr, acc, 0, 0, 0);
        }
        __syncthreads();
#pragma unroll
        for (int i = 0; i < 4; ++i) {
          int q2 = i * 512 + tid;
          int n = q2 >> 4, k8 = (q2 & 15) * 8;
          *(f16x8*)(&Bs[n][k8]) = *(const f16x8*)(WdTp + (size_t)(c0 + n) * 256 + 128 + k8);
        }
        __syncthreads();
#pragma unroll
        for (int ks = 4; ks < 8; ++ks) {
          f16x8 bfr = *(const f16x8*)(&Bs[w * 16 + l15][(ks - 4) * 32 + lq * 8]);
          acc = __builtin_amdgcn_mfma_f32_16x16x32_f16(a[ks], bfr, acc, 0, 0, 0);
        }
        float bvv = bd[ncol];
#pragma unroll
        for (int r = 0; r < 4; ++r)
          lg[lq * 4 + r][ncol] = (_Float16)(acc[r] + bvv);
      }
      __syncthreads();

      const int row = tid >> 5, j = tid & 31;
      float mx = -1e30f;
#pragma unroll
      for (int k = 0; k < 32; ++k)
        mx = fmaxf(mx, (float)lg[row][j + k * 32]);
#pragma unroll
      for (int m = 1; m < 32; m <<= 1)
        mx = fmaxf(mx, __shfl_xor(mx, m, 64));
      float s = 0.f;
#pragma unroll
      for (int k = 0; k < 32; ++k)
        s += __builtin_amdgcn_exp2f(((float)lg[row][j + k * 32] - mx) * 1.44269504088896f);
#pragma unroll
      for (int m = 1; m < 32; m <<= 1)
        s += __shfl_xor(s, m, 64);
      const float rinv = __builtin_amdgcn_rcpf(s);
      float* orow = out + (size_t)(m0 + row) * 1024;
#pragma unroll
      for (int k = 0; k < 8; ++k) {
        int c = k * 128 + j * 4;
        f32x4 vv;
#pragma unroll
        for (int u = 0; u < 4; ++u)
          vv[u] = __builtin_amdgcn_exp2f(((float)lg[row][c + u] - mx) * 1.44269504088896f) * rinv;
        *(f32x4*)(orow + c) = vv;
      }
      __syncthreads();                     // lg readers done before next tile
    }
  }
}

// ---------------------------------------------------------------------------
extern "C" void kernel_launch(void* const* d_in, const int* in_sizes, int n_in,
                              void* d_out, int out_size, void* d_ws, size_t ws_size,
                              hipStream_t stream) {
  const float* X  = (const float*)d_in[0];
  const float* Wx = (const float*)d_in[1];
  const float* Wh = (const float*)d_in[2];
  const float* bv = (const float*)d_in[3];
  const float* Wd = (const float*)d_in[4];
  const float* bd = (const float*)d_in[5];
  float* out = (float*)d_out;

  char* ws = (char*)d_ws;
  float*    xp_packed = (float*)(ws);                              // 16 MB
  _Float16* Yt    = (_Float16*)(ws + (16u << 20));                 // 8 MB
  _Float16* WxT   = (_Float16*)(ws + (24u << 20));                 // 512 KB
  _Float16* WhTp  = (_Float16*)(ws + (24u << 20) + (512u << 10));  // 128 KB
  _Float16* WdTp  = (_Float16*)(ws + (24u << 20) + (640u << 10));  // 512 KB
  int*      cnt1  = (int*)(ws + (26u << 20));                      // 16 ints
  int*      sc    = cnt1 + 16;                                     // 16 ints

  (void)hipFuncSetAttribute((const void*)k_fused,
                            hipFuncAttributeMaxDynamicSharedMemorySize, 86016);

  (void)hipMemsetAsync(cnt1, 0, 128, stream);
  k_transpose_cast<<<dim3(8, 32), 256, 0, stream>>>(Wx, WxT, 1024, 256);
  k_transpose_cast_perm<<<dim3(8, 8),  256, 0, stream>>>(Wh, WhTp, 256, 256);
  k_transpose_cast_perm<<<dim3(32, 8), 256, 0, stream>>>(Wd, WdTp, 256, 1024);
  k_fused<<<dim3(256), dim3(512), 86016, stream>>>(
      X, WxT, bv, xp_packed, WhTp, Yt, out + 16384 * 1024, WdTp, bd, out,
      cnt1, sc);
}